// Round 8
// baseline (1646.757 us; speedup 1.0000x reference)
//
#include <hip/hip_runtime.h>
#include <math.h>

#define NT 256
#define G 4

// fp32 problem (validated R6/R7). G=4 batches/block. Round-8: bf16 X in LDS,
// wave-parallel conflict-free scores, no split-K projections, padded xbar.

enum {
  I_LEAF = 0, I_SUB, I_SAW, I_SAB, I_LAW, I_LAB, I_PAW, I_PAB,
  I_SCLS, I_SWQKV, I_SBQKV, I_SWO, I_SBO, I_SLNG, I_SLNB, I_SW1, I_SB1, I_SW2, I_SB2,
  I_PCLS, I_PWQKV, I_PBQKV, I_PWO, I_PBO, I_PLNG, I_PLNB, I_PW1, I_PB1, I_PW2, I_PB2,
  I_CLFW, I_CLFB
};

struct P {
  const float* in[32];
  float* parent_al;  // ws [B][2][128]
  float* vecs;       // ws [B][3][128]
  float* out;        // [B][2]
};

using u16 = unsigned short;

__device__ __forceinline__ float uplo(unsigned int u) { return __uint_as_float(u << 16); }
__device__ __forceinline__ float uphi(unsigned int u) { return __uint_as_float(u & 0xffff0000u); }
__device__ __forceinline__ float B16F(u16 v) { return __uint_as_float((unsigned int)v << 16); }
__device__ __forceinline__ u16 F2B(float f) {  // RNE
  unsigned int u = __float_as_uint(f);
  return (u16)((u + 0x7FFFu + ((u >> 16) & 1u)) >> 16);
}
__device__ __forceinline__ void LD8(const float* p, float* o) {
  float4 a = ((const float4*)p)[0], b = ((const float4*)p)[1];
  o[0] = a.x; o[1] = a.y; o[2] = a.z; o[3] = a.w;
  o[4] = b.x; o[5] = b.y; o[6] = b.z; o[7] = b.w;
}
__device__ __forceinline__ void fma8(float& acc, const float* x, const float* w) {
#pragma unroll
  for (int i = 0; i < 8; ++i) acc += x[i] * w[i];
}
__device__ __forceinline__ float gelu(float v) {
  return 0.5f * v * (1.0f + erff(v * 0.70710678118654752f));
}

// LayerNorm rows in place: buf [G][E]; one wave per row (G=4).
template <int E>
__device__ void ln_rows(float* buf, const float* __restrict__ gg, const float* __restrict__ bb) {
  const int w = threadIdx.x >> 6, lane = threadIdx.x & 63;
  for (int g = w; g < G; g += 4) {
    float* row = buf + g * E;
    float s = 0.f, s2 = 0.f;
    for (int e = lane; e < E; e += 64) { float x = row[e]; s += x; s2 += x * x; }
#pragma unroll
    for (int off = 1; off < 64; off <<= 1) {
      s += __shfl_xor(s, off, 64);
      s2 += __shfl_xor(s2, off, 64);
    }
    float m = s / (float)E;
    float inv = 1.0f / sqrtf(s2 / (float)E - m * m + 1e-5f);
    for (int e = lane; e < E; e += 64) row[e] = (row[e] - m) * inv * gg[e] + bb[e];
  }
}

// q = Wq.cls + bq ; u_h = scale * Wk_h^T q_h ; sb_h = scale * q_h.bk_h
template <int E>
__device__ void compute_usb(const float* __restrict__ Wq, const float* __restrict__ bq,
                            const float* __restrict__ clsb, float* qb,
                            float* uL, float* sbL) {
  const int tid = threadIdx.x;
  constexpr int D = E / 4;
  const float scale = (D == 16) ? 0.25f : 0.17677669529663687f;
  if (tid < E) {
    float acc = bq[tid];
    const float* w = Wq + (size_t)tid * E;
    for (int k = 0; k < E; k += 8) {
      float wv[8];
      LD8(w + k, wv);
#pragma unroll
      for (int ii = 0; ii < 8; ++ii) acc += clsb[k + ii] * wv[ii];
    }
    qb[tid] = acc;
  }
  __syncthreads();
  if (tid < E) {
    for (int h = 0; h < 4; ++h) {
      float acc = 0.f;
      for (int d = 0; d < D; ++d)
        acc += Wq[(size_t)(E + h * D + d) * E + tid] * qb[h * D + d];
      uL[h * E + tid] = acc * scale;
    }
  }
  if (tid < 4) {
    float acc = 0.f;
    for (int d = 0; d < D; ++d) acc += qb[tid * D + d] * bq[E + tid * D + d];
    sbL[tid] = acc * scale;
  }
  __syncthreads();
}

// Folded CLS-only aggregator over G batches.
// X: LDS bf16 tokens, row (t*G+g) of E elements. Result fp32 [G][E] in o.
// xbar stride XBS = E+4 (bank-spread). Ends with __syncthreads().
template <int E, int T>
__device__ void agg_run(const u16* __restrict__ X, const float* __restrict__ clsb,
                        const float* __restrict__ uL, const float* __restrict__ sbL,
                        const float* __restrict__ Wv, const float* __restrict__ bv,
                        const float* __restrict__ Wo, const float* __restrict__ bo,
                        const float* __restrict__ lng, const float* __restrict__ lnb,
                        const float* __restrict__ W1, const float* __restrict__ b1,
                        const float* __restrict__ W2, const float* __restrict__ b2,
                        float* att, float* xbar, float* o, float* h, float* mid) {
  const int tid = threadIdx.x;
  const int wid = tid >> 6, lane = tid & 63;
  constexpr int S = T + 1, D = E / 4, XBS = E + 4;
  constexpr int GPT = (G * E) / NT;          // outputs/thread in projections
  constexpr int M1 = (4 * E) / NT;           // FFN1 outputs/thread

  // ---- scores[g][h][s] = sb[h] + x_s . u_h : one dot per wave-iteration ----
  for (int i = wid; i < G * 4 * S; i += 4) {
    int s = i % S, hh = (i / S) % 4, g = i / (4 * S);
    float part = 0.f;
    if (lane < E / 2) {
      float2 u2 = ((const float2*)(uL + hh * E))[lane];
      if (s == 0) {
        float2 c2 = ((const float2*)clsb)[lane];
        part = c2.x * u2.x + c2.y * u2.y;
      } else {
        unsigned int xv = ((const unsigned int*)(X + ((s - 1) * G + g) * E))[lane];
        part = uplo(xv) * u2.x + uphi(xv) * u2.y;
      }
    }
#pragma unroll
    for (int off = 1; off < 64; off <<= 1) part += __shfl_xor(part, off, 64);
    if (lane == 0) att[(g * 4 + hh) * S + s] = sbL[hh] + part;
  }
  __syncthreads();
  // ---- softmax over s ----
  for (int i = tid; i < G * 4; i += NT) {
    float* a = att + i * S;
    float mx = a[0];
    for (int s = 1; s < S; ++s) mx = fmaxf(mx, a[s]);
    float sum = 0.f;
    for (int s = 0; s < S; ++s) { float e = expf(a[s] - mx); a[s] = e; sum += e; }
    float inv = 1.0f / sum;
    for (int s = 0; s < S; ++s) a[s] *= inv;
  }
  __syncthreads();
  // ---- xbar[g][h][k] = a0*cls[k] + sum_s att * x_s[k]  (lanes: consecutive k) ----
  for (int i = tid; i < G * 4 * E; i += NT) {
    int k = i % E, hh = (i / E) % 4, g = i / (4 * E);
    const float* a = att + (g * 4 + hh) * S;
    float acc = a[0] * clsb[k];
    for (int s = 1; s < S; ++s) acc += a[s] * B16F(X[((s - 1) * G + g) * E + k]);
    xbar[(g * 4 + hh) * XBS + k] = acc;
  }
  __syncthreads();
  // ---- o[g][e] = bv[e] + Wv[e][:] . xbar[g][head(e)][:]  (GPT g's per thread) ----
  {
    const int e = tid % E, gp = tid / E, hh = e / D;
    const float* w = Wv + (size_t)e * E;
    float acc[GPT];
#pragma unroll
    for (int r = 0; r < GPT; ++r) acc[r] = 0.f;
    for (int kc = 0; kc < E; kc += 8) {
      float wv[8];
      LD8(w + kc, wv);
#pragma unroll
      for (int r = 0; r < GPT; ++r) {
        float xv[8];
        LD8(xbar + ((gp * GPT + r) * 4 + hh) * XBS + kc, xv);
        fma8(acc[r], xv, wv);
      }
    }
#pragma unroll
    for (int r = 0; r < GPT; ++r) o[(gp * GPT + r) * E + e] = bv[e] + acc[r];
  }
  __syncthreads();
  // ---- h[g][e] = bo[e] + cls[e] + Wo[e][:] . o[g][:] ----
  {
    const int e = tid % E, gp = tid / E;
    const float* w = Wo + (size_t)e * E;
    float acc[GPT];
#pragma unroll
    for (int r = 0; r < GPT; ++r) acc[r] = 0.f;
    for (int kc = 0; kc < E; kc += 8) {
      float wv[8];
      LD8(w + kc, wv);
#pragma unroll
      for (int r = 0; r < GPT; ++r) {
        float xv[8];
        LD8(o + (gp * GPT + r) * E + kc, xv);
        fma8(acc[r], xv, wv);
      }
    }
#pragma unroll
    for (int r = 0; r < GPT; ++r) {
      int g = gp * GPT + r;
      h[g * E + e] = bo[e] + clsb[e] + acc[r];
    }
  }
  __syncthreads();
  ln_rows<E>(h, lng, lnb);
  __syncthreads();
  // ---- FFN1: mid[g][m] = gelu(h[g] @ W1 + b1), m = tid*M1 + r ----
  {
    float acc[M1][G];
#pragma unroll
    for (int r = 0; r < M1; ++r)
#pragma unroll
      for (int g = 0; g < G; ++g) acc[r][g] = 0.f;
    for (int j = 0; j < E; j += 8) {
      float wv[M1][8];
#pragma unroll
      for (int ii = 0; ii < 8; ++ii) {
        if constexpr (M1 == 2) {
          float2 w2 = *(const float2*)(W1 + (size_t)(j + ii) * 4 * E + 2 * tid);
          wv[0][ii] = w2.x;
          wv[1][ii] = w2.y;
        } else {
          wv[0][ii] = W1[(size_t)(j + ii) * 4 * E + tid];
        }
      }
#pragma unroll
      for (int g = 0; g < G; ++g) {
        float xv[8];
        LD8(h + g * E + j, xv);
#pragma unroll
        for (int r = 0; r < M1; ++r) fma8(acc[r][g], xv, wv[r]);
      }
    }
#pragma unroll
    for (int r = 0; r < M1; ++r) {
      int m = tid * M1 + r;
      float bias = b1[m];
#pragma unroll
      for (int g = 0; g < G; ++g) mid[g * 4 * E + m] = gelu(acc[r][g] + bias);
    }
  }
  __syncthreads();
  // ---- o[g][e] = LN(h + mid @ W2 + b2) ----
  {
    const int e = tid % E, gp = tid / E;
    float acc[GPT];
#pragma unroll
    for (int r = 0; r < GPT; ++r) acc[r] = 0.f;
    for (int m = 0; m < 4 * E; m += 8) {
      float wv[8];
#pragma unroll
      for (int ii = 0; ii < 8; ++ii) wv[ii] = W2[(size_t)(m + ii) * E + e];
#pragma unroll
      for (int r = 0; r < GPT; ++r) {
        float xv[8];
        LD8(mid + (gp * GPT + r) * 4 * E + m, xv);
        fma8(acc[r], xv, wv);
      }
    }
#pragma unroll
    for (int r = 0; r < GPT; ++r) {
      int g = gp * GPT + r;
      o[g * E + e] = b2[e] + h[g * E + e] + acc[r];
    }
  }
  __syncthreads();
  ln_rows<E>(o, lng, lnb);
  __syncthreads();
}

// ===================== kernel 1: sub path =====================
__global__ __launch_bounds__(NT) void k_sub(P p) {
  __shared__ __align__(16) u16 X1[8 * G * 64];
  __shared__ __align__(16) u16 X2[3 * G * 64];
  __shared__ __align__(16) float feats[G * 11 * 32];
  __shared__ __align__(16) float clsb[64];
  __shared__ __align__(16) float qb[64];
  __shared__ __align__(16) float uL[4 * 64];
  __shared__ __align__(16) float sbL[4];
  __shared__ __align__(16) float att[G * 4 * 9];
  __shared__ __align__(16) float xbar[G * 4 * 68];
  __shared__ __align__(16) float ob[G * 64];
  __shared__ __align__(16) float hb[G * 64];
  __shared__ __align__(16) float mid[G * 256];
  __shared__ __align__(16) float vec1[G * 64];
  const int tid = threadIdx.x, b0 = blockIdx.x * G;

  const float* subf = p.in[I_SUB];
  for (int i = tid; i < G * 11 * 32; i += NT) {
    int g = i / (11 * 32), r = i % (11 * 32);
    feats[i] = subf[(size_t)(b0 + g) * 352 + r];
  }
  __syncthreads();

  const float* saW = p.in[I_SAW];
  const float* sab = p.in[I_SAB];
  for (int i = tid; i < 11 * 64; i += NT) {
    int f = i / 64, e = i % 64;
    float bias = sab[f * 64 + e];
    float acc[G];
#pragma unroll
    for (int g = 0; g < G; ++g) acc[g] = bias;
    for (int d = 0; d < 32; d += 8) {
      float wv[8];
#pragma unroll
      for (int ii = 0; ii < 8; ++ii) wv[ii] = saW[(size_t)(f * 32 + d + ii) * 64 + e];
#pragma unroll
      for (int g = 0; g < G; ++g) {
        float xv[8];
        LD8(feats + (g * 11 + f) * 32 + d, xv);
        fma8(acc[g], xv, wv);
      }
    }
#pragma unroll
    for (int g = 0; g < G; ++g) {
      if (f < 8) X1[(f * G + g) * 64 + e] = F2B(acc[g]);
      else       X2[((f - 8) * G + g) * 64 + e] = F2B(acc[g]);
    }
  }
  __syncthreads();

  // agg1: tcp.flags (subfields 0..7)
  if (tid < 64) clsb[tid] = p.in[I_SCLS][tid];
  __syncthreads();
  compute_usb<64>(p.in[I_SWQKV], p.in[I_SBQKV], clsb, qb, uL, sbL);
  agg_run<64, 8>(X1, clsb, uL, sbL,
                 p.in[I_SWQKV] + 2 * 64 * 64, p.in[I_SBQKV] + 128,
                 p.in[I_SWO], p.in[I_SBO], p.in[I_SLNG], p.in[I_SLNB],
                 p.in[I_SW1], p.in[I_SB1], p.in[I_SW2], p.in[I_SB2],
                 att, xbar, ob, hb, mid);
  for (int i = tid; i < G * 64; i += NT) vec1[i] = ob[i];
  __syncthreads();

  // agg2: ip.flags (subfields 8..10)
  if (tid < 64) clsb[tid] = p.in[I_SCLS][64 + tid];
  __syncthreads();
  compute_usb<64>(p.in[I_SWQKV] + 192 * 64, p.in[I_SBQKV] + 192, clsb, qb, uL, sbL);
  agg_run<64, 3>(X2, clsb, uL, sbL,
                 p.in[I_SWQKV] + 192 * 64 + 2 * 64 * 64, p.in[I_SBQKV] + 192 + 128,
                 p.in[I_SWO] + 64 * 64, p.in[I_SBO] + 64,
                 p.in[I_SLNG] + 64, p.in[I_SLNB] + 64,
                 p.in[I_SW1] + 64 * 256, p.in[I_SB1] + 256,
                 p.in[I_SW2] + 256 * 64, p.in[I_SB2] + 64,
                 att, xbar, ob, hb, mid);

  // parent_al: [:,0] = tcpf @ paW0 + pab0 ; [:,1] = ipf @ paW1 + pab1
  {
    const int pi = tid >> 7, e = tid & 127;
    const float* paW = p.in[I_PAW];
    float bias = p.in[I_PAB][pi * 128 + e];
    float acc[G];
#pragma unroll
    for (int g = 0; g < G; ++g) acc[g] = bias;
    const float* src = pi ? ob : vec1;
    for (int j = 0; j < 64; j += 8) {
      float wv[8];
#pragma unroll
      for (int ii = 0; ii < 8; ++ii) wv[ii] = paW[(size_t)(pi * 64 + j + ii) * 128 + e];
#pragma unroll
      for (int g = 0; g < G; ++g) {
        float xv[8];
        LD8(src + g * 64 + j, xv);
        fma8(acc[g], xv, wv);
      }
    }
#pragma unroll
    for (int g = 0; g < G; ++g)
      p.parent_al[(size_t)(b0 + g) * 256 + pi * 128 + e] = acc[g];
  }
}

// ===================== kernel 2: parent aggs =====================
template <int T, int F, int F0, int PAR, int AI>
__device__ void parent_body(const P& p, int b0, u16* X, float* clsb, float* qb,
                            float* uL, float* sbL, float* att, float* xbar,
                            float* ob, float* hb, float* mid, float* feats) {
  const int tid = threadIdx.x;
  const float* leaf = p.in[I_LEAF];
  for (int i = tid; i < G * F * 32; i += NT) {
    int g = i / (F * 32), r = i % (F * 32);
    feats[i] = leaf[(size_t)(b0 + g) * 1088 + F0 * 32 + r];
  }
  __syncthreads();
  const float* laW = p.in[I_LAW];
  const float* lab = p.in[I_LAB];
  for (int i = tid; i < F * 128; i += NT) {
    int f = i / 128, e = i % 128;
    float bias = lab[(F0 + f) * 128 + e];
    float acc[G];
#pragma unroll
    for (int g = 0; g < G; ++g) acc[g] = bias;
    for (int d = 0; d < 32; d += 8) {
      float wv[8];
#pragma unroll
      for (int ii = 0; ii < 8; ++ii)
        wv[ii] = laW[(size_t)((F0 + f) * 32 + d + ii) * 128 + e];
#pragma unroll
      for (int g = 0; g < G; ++g) {
        float xv[8];
        LD8(feats + (g * F + f) * 32 + d, xv);
        fma8(acc[g], xv, wv);
      }
    }
#pragma unroll
    for (int g = 0; g < G; ++g) X[(f * G + g) * 128 + e] = F2B(acc[g]);
  }
  if (PAR >= 0) {
    for (int i = tid; i < G * 128; i += NT) {
      int g = i / 128, e = i % 128;
      X[((T - 1) * G + g) * 128 + e] =
          F2B(p.parent_al[(size_t)(b0 + g) * 256 + PAR * 128 + e]);
    }
  }
  if (tid < 128) clsb[tid] = p.in[I_PCLS][AI * 128 + tid];
  __syncthreads();
  compute_usb<128>(p.in[I_PWQKV] + (size_t)AI * 384 * 128, p.in[I_PBQKV] + AI * 384,
                   clsb, qb, uL, sbL);
  agg_run<128, T>(X, clsb, uL, sbL,
                  p.in[I_PWQKV] + (size_t)AI * 384 * 128 + 2 * 128 * 128,
                  p.in[I_PBQKV] + AI * 384 + 256,
                  p.in[I_PWO] + (size_t)AI * 128 * 128, p.in[I_PBO] + AI * 128,
                  p.in[I_PLNG] + AI * 128, p.in[I_PLNB] + AI * 128,
                  p.in[I_PW1] + (size_t)AI * 128 * 512, p.in[I_PB1] + AI * 512,
                  p.in[I_PW2] + (size_t)AI * 512 * 128, p.in[I_PB2] + AI * 128,
                  att, xbar, ob, hb, mid);
  for (int i = tid; i < G * 128; i += NT) {
    int e = i % 128, g = i / 128;
    p.vecs[(size_t)(b0 + g) * 384 + AI * 128 + e] = ob[g * 128 + e];
  }
}

__global__ __launch_bounds__(NT) void k_parent(P p) {
  __shared__ __align__(16) u16 X[16 * G * 128];
  __shared__ __align__(16) float feats[G * 15 * 32];
  __shared__ __align__(16) float clsb[128];
  __shared__ __align__(16) float qb[128];
  __shared__ __align__(16) float uL[4 * 128];
  __shared__ __align__(16) float sbL[4];
  __shared__ __align__(16) float att[G * 4 * 17];
  __shared__ __align__(16) float xbar[G * 4 * 132];
  __shared__ __align__(16) float ob[G * 128];
  __shared__ __align__(16) float hb[G * 128];
  __shared__ __align__(16) float mid[G * 512];
  const int b0 = blockIdx.x * G;
  if (blockIdx.y == 0)
    parent_body<8, 8, 0, -1, 0>(p, b0, X, clsb, qb, uL, sbL, att, xbar, ob, hb, mid, feats);
  else if (blockIdx.y == 1)
    parent_body<12, 11, 8, 1, 1>(p, b0, X, clsb, qb, uL, sbL, att, xbar, ob, hb, mid, feats);
  else
    parent_body<16, 15, 19, 0, 2>(p, b0, X, clsb, qb, uL, sbL, att, xbar, ob, hb, mid, feats);
}

// ===================== kernel 3: pkt agg + classifier =====================
__global__ __launch_bounds__(NT) void k_pkt(P p) {
  __shared__ __align__(16) u16 X[3 * G * 128];
  __shared__ __align__(16) float clsb[128];
  __shared__ __align__(16) float qb[128];
  __shared__ __align__(16) float uL[4 * 128];
  __shared__ __align__(16) float sbL[4];
  __shared__ __align__(16) float att[G * 4 * 4];
  __shared__ __align__(16) float xbar[G * 4 * 132];
  __shared__ __align__(16) float ob[G * 128];
  __shared__ __align__(16) float hb[G * 128];
  __shared__ __align__(16) float mid[G * 512];
  const int tid = threadIdx.x, b0 = blockIdx.x * G;

  for (int i = tid; i < 3 * G * 128; i += NT) {
    int e = i % 128, g = (i / 128) % G, t = i / (G * 128);
    X[(t * G + g) * 128 + e] = F2B(p.vecs[(size_t)(b0 + g) * 384 + t * 128 + e]);
  }
  if (tid < 128) clsb[tid] = p.in[I_PCLS][3 * 128 + tid];
  __syncthreads();
  compute_usb<128>(p.in[I_PWQKV] + (size_t)3 * 384 * 128, p.in[I_PBQKV] + 3 * 384,
                   clsb, qb, uL, sbL);
  agg_run<128, 3>(X, clsb, uL, sbL,
                  p.in[I_PWQKV] + (size_t)3 * 384 * 128 + 2 * 128 * 128,
                  p.in[I_PBQKV] + 3 * 384 + 256,
                  p.in[I_PWO] + (size_t)3 * 128 * 128, p.in[I_PBO] + 3 * 128,
                  p.in[I_PLNG] + 3 * 128, p.in[I_PLNB] + 3 * 128,
                  p.in[I_PW1] + (size_t)3 * 128 * 512, p.in[I_PB1] + 3 * 512,
                  p.in[I_PW2] + (size_t)3 * 512 * 128, p.in[I_PB2] + 3 * 128,
                  att, xbar, ob, hb, mid);

  if (tid < G * 2) {
    int g = tid >> 1, c = tid & 1;
    const float* cw = p.in[I_CLFW];
    float acc = p.in[I_CLFB][c];
    for (int j = 0; j < 128; ++j) acc += ob[g * 128 + j] * cw[j * 2 + c];
    p.out[(size_t)(b0 + g) * 2 + c] = acc;
  }
}

extern "C" void kernel_launch(void* const* d_in, const int* in_sizes, int n_in,
                              void* d_out, int out_size, void* d_ws, size_t ws_size,
                              hipStream_t stream) {
  P p;
  for (int i = 0; i < 32; ++i) p.in[i] = (const float*)d_in[i];
  const int B = in_sizes[0] / (34 * 32);
  float* ws = (float*)d_ws;
  p.parent_al = ws;                        // B*256 floats
  p.vecs = ws + (size_t)B * 256;           // B*384 floats
  p.out = (float*)d_out;

  k_sub<<<dim3(B / G), dim3(NT), 0, stream>>>(p);
  k_parent<<<dim3(B / G, 3), dim3(NT), 0, stream>>>(p);
  k_pkt<<<dim3(B / G), dim3(NT), 0, stream>>>(p);
}

// Round 9
// 1407.384 us; speedup vs baseline: 1.1701x; 1.1701x over previous
//
#include <hip/hip_runtime.h>
#include <math.h>

#define NT 256
#define G 4

// fp32 problem. R9: coalesced k-split dots (ks=tid&7) + shfl reduce for
// Wv/Wo/q, no feats staging, no partial buffer, LDS 40.5KB -> 4 blocks/CU.

enum {
  I_LEAF = 0, I_SUB, I_SAW, I_SAB, I_LAW, I_LAB, I_PAW, I_PAB,
  I_SCLS, I_SWQKV, I_SBQKV, I_SWO, I_SBO, I_SLNG, I_SLNB, I_SW1, I_SB1, I_SW2, I_SB2,
  I_PCLS, I_PWQKV, I_PBQKV, I_PWO, I_PBO, I_PLNG, I_PLNB, I_PW1, I_PB1, I_PW2, I_PB2,
  I_CLFW, I_CLFB
};

struct P {
  const float* in[32];
  float* parent_al;  // ws [B][2][128]
  float* vecs;       // ws [B][3][128]
  float* out;        // [B][2]
};

using u16 = unsigned short;

__device__ __forceinline__ float uplo(unsigned int u) { return __uint_as_float(u << 16); }
__device__ __forceinline__ float uphi(unsigned int u) { return __uint_as_float(u & 0xffff0000u); }
__device__ __forceinline__ float B16F(u16 v) { return __uint_as_float((unsigned int)v << 16); }
__device__ __forceinline__ u16 F2B(float f) {  // RNE
  unsigned int u = __float_as_uint(f);
  return (u16)((u + 0x7FFFu + ((u >> 16) & 1u)) >> 16);
}
__device__ __forceinline__ void LD8(const float* p, float* o) {
  float4 a = ((const float4*)p)[0], b = ((const float4*)p)[1];
  o[0] = a.x; o[1] = a.y; o[2] = a.z; o[3] = a.w;
  o[4] = b.x; o[5] = b.y; o[6] = b.z; o[7] = b.w;
}
__device__ __forceinline__ void fma8(float& acc, const float* x, const float* w) {
#pragma unroll
  for (int i = 0; i < 8; ++i) acc += x[i] * w[i];
}
__device__ __forceinline__ float red8(float v) {  // reduce within 8 consecutive lanes
  v += __shfl_xor(v, 1, 64);
  v += __shfl_xor(v, 2, 64);
  v += __shfl_xor(v, 4, 64);
  return v;
}
__device__ __forceinline__ float gelu(float v) {
  return 0.5f * v * (1.0f + erff(v * 0.70710678118654752f));
}

// LayerNorm rows in place: buf [G][E]; one wave per row (G=4).
template <int E>
__device__ void ln_rows(float* buf, const float* __restrict__ gg, const float* __restrict__ bb) {
  const int w = threadIdx.x >> 6, lane = threadIdx.x & 63;
  for (int g = w; g < G; g += 4) {
    float* row = buf + g * E;
    float s = 0.f, s2 = 0.f;
    for (int e = lane; e < E; e += 64) { float x = row[e]; s += x; s2 += x * x; }
#pragma unroll
    for (int off = 1; off < 64; off <<= 1) {
      s += __shfl_xor(s, off, 64);
      s2 += __shfl_xor(s2, off, 64);
    }
    float m = s / (float)E;
    float inv = 1.0f / sqrtf(s2 / (float)E - m * m + 1e-5f);
    for (int e = lane; e < E; e += 64) row[e] = (row[e] - m) * inv * gg[e] + bb[e];
  }
}

// q = Wq.cls + bq (coalesced k-split) ; u_h = scale*Wk_h^T q_h ; sb_h = scale*q_h.bk_h
// qb may alias a scratch buffer reused later (no overlap in time).
template <int E>
__device__ void compute_usb(const float* __restrict__ Wq, const float* __restrict__ bq,
                            const float* __restrict__ clsb, float* qb,
                            float* uL, float* sbL) {
  const int tid = threadIdx.x;
  constexpr int D = E / 4;
  const float scale = (D == 16) ? 0.25f : 0.17677669529663687f;
  const int ks = tid & 7, eb = tid >> 3;
  for (int e = eb; e < E; e += NT / 8) {
    const float* w = Wq + (size_t)e * E + ks * 8;
    float acc = 0.f;
    for (int kc = 0; kc < E; kc += 64) {
      float wv[8], xv[8];
      LD8(w + kc, wv);
      LD8(clsb + kc + ks * 8, xv);
      fma8(acc, xv, wv);
    }
    acc = red8(acc);
    if (ks == 0) qb[e] = bq[e] + acc;
  }
  __syncthreads();
  if (tid < E) {
    for (int h = 0; h < 4; ++h) {
      float acc = 0.f;
      for (int d = 0; d < D; ++d)
        acc += Wq[(size_t)(E + h * D + d) * E + tid] * qb[h * D + d];
      uL[h * E + tid] = acc * scale;
    }
  }
  if (tid < 4) {
    float acc = 0.f;
    for (int d = 0; d < D; ++d) acc += qb[tid * D + d] * bq[E + tid * D + d];
    sbL[tid] = acc * scale;
  }
  __syncthreads();
}

// Folded CLS-only aggregator over G batches. X: LDS bf16, row (t*G+g), E elems.
// Result fp32 [G][E] in ob. Ends with __syncthreads().
template <int E, int T>
__device__ void agg_run(const u16* __restrict__ X, const float* __restrict__ clsb,
                        const float* __restrict__ uL, const float* __restrict__ sbL,
                        const float* __restrict__ Wv, const float* __restrict__ bv,
                        const float* __restrict__ Wo, const float* __restrict__ bo,
                        const float* __restrict__ lng, const float* __restrict__ lnb,
                        const float* __restrict__ W1, const float* __restrict__ b1,
                        const float* __restrict__ W2, const float* __restrict__ b2,
                        float* att, float* xbar, float* ob, float* hb, float* mid) {
  const int tid = threadIdx.x;
  const int wid = tid >> 6, lane = tid & 63;
  const int ks = tid & 7, eb = tid >> 3;
  constexpr int S = T + 1, D = E / 4;
  constexpr int GPT = (G * E) / NT;          // outputs/thread in FFN2
  constexpr int M1 = (4 * E) / NT;           // FFN1 outputs/thread

  // ---- scores[g][h][s] = sb[h] + x_s . u_h : one dot per wave-iteration ----
  for (int i = wid; i < G * 4 * S; i += 4) {
    int s = i % S, hh = (i / S) % 4, g = i / (4 * S);
    float part = 0.f;
    if (lane < E / 2) {
      float2 u2 = ((const float2*)(uL + hh * E))[lane];
      if (s == 0) {
        float2 c2 = ((const float2*)clsb)[lane];
        part = c2.x * u2.x + c2.y * u2.y;
      } else {
        unsigned int xv = ((const unsigned int*)(X + ((s - 1) * G + g) * E))[lane];
        part = uplo(xv) * u2.x + uphi(xv) * u2.y;
      }
    }
#pragma unroll
    for (int off = 1; off < 64; off <<= 1) part += __shfl_xor(part, off, 64);
    if (lane == 0) att[(g * 4 + hh) * S + s] = sbL[hh] + part;
  }
  __syncthreads();
  // ---- softmax over s ----
  for (int i = tid; i < G * 4; i += NT) {
    float* a = att + i * S;
    float mx = a[0];
    for (int s = 1; s < S; ++s) mx = fmaxf(mx, a[s]);
    float sum = 0.f;
    for (int s = 0; s < S; ++s) { float e = expf(a[s] - mx); a[s] = e; sum += e; }
    float inv = 1.0f / sum;
    for (int s = 0; s < S; ++s) a[s] *= inv;
  }
  __syncthreads();
  // ---- xbar[g][h][k] = a0*cls[k] + sum_s att * x_s[k] ----
  for (int i = tid; i < G * 4 * E; i += NT) {
    int k = i % E, hh = (i / E) % 4, g = i / (4 * E);
    const float* a = att + (g * 4 + hh) * S;
    float acc = a[0] * clsb[k];
    for (int s = 1; s < S; ++s) acc += a[s] * B16F(X[((s - 1) * G + g) * E + k]);
    xbar[(g * 4 + hh) * E + k] = acc;
  }
  __syncthreads();
  // ---- ob[g][e] = bv[e] + Wv[e][:] . xbar[g][head(e)][:]  (k-split, coalesced) ----
  for (int e = eb; e < E; e += NT / 8) {
    const int hh = e / D;
    const float* w = Wv + (size_t)e * E + ks * 8;
    float acc[G];
#pragma unroll
    for (int g = 0; g < G; ++g) acc[g] = 0.f;
    for (int kc = 0; kc < E; kc += 64) {
      float wv[8];
      LD8(w + kc, wv);
#pragma unroll
      for (int g = 0; g < G; ++g) {
        float xv[8];
        LD8(xbar + (g * 4 + hh) * E + kc + ks * 8, xv);
        fma8(acc[g], xv, wv);
      }
    }
#pragma unroll
    for (int g = 0; g < G; ++g) {
      float v = red8(acc[g]);
      if (ks == 0) ob[g * E + e] = bv[e] + v;
    }
  }
  __syncthreads();
  // ---- hb[g][e] = bo[e] + cls[e] + Wo[e][:] . ob[g][:]  (k-split, coalesced) ----
  for (int e = eb; e < E; e += NT / 8) {
    const float* w = Wo + (size_t)e * E + ks * 8;
    float acc[G];
#pragma unroll
    for (int g = 0; g < G; ++g) acc[g] = 0.f;
    for (int kc = 0; kc < E; kc += 64) {
      float wv[8];
      LD8(w + kc, wv);
#pragma unroll
      for (int g = 0; g < G; ++g) {
        float xv[8];
        LD8(ob + g * E + kc + ks * 8, xv);
        fma8(acc[g], xv, wv);
      }
    }
#pragma unroll
    for (int g = 0; g < G; ++g) {
      float v = red8(acc[g]);
      if (ks == 0) hb[g * E + e] = bo[e] + clsb[e] + v;
    }
  }
  __syncthreads();
  ln_rows<E>(hb, lng, lnb);
  __syncthreads();
  // ---- FFN1: mid[g][m] = gelu(hb[g] @ W1 + b1)  (coalesced over m) ----
  {
    float acc[M1][G];
#pragma unroll
    for (int r = 0; r < M1; ++r)
#pragma unroll
      for (int g = 0; g < G; ++g) acc[r][g] = 0.f;
    for (int j = 0; j < E; j += 8) {
      float wv[M1][8];
#pragma unroll
      for (int ii = 0; ii < 8; ++ii) {
        if constexpr (M1 == 2) {
          float2 w2 = *(const float2*)(W1 + (size_t)(j + ii) * 4 * E + 2 * tid);
          wv[0][ii] = w2.x;
          wv[1][ii] = w2.y;
        } else {
          wv[0][ii] = W1[(size_t)(j + ii) * 4 * E + tid];
        }
      }
#pragma unroll
      for (int g = 0; g < G; ++g) {
        float xv[8];
        LD8(hb + g * E + j, xv);
#pragma unroll
        for (int r = 0; r < M1; ++r) fma8(acc[r][g], xv, wv[r]);
      }
    }
#pragma unroll
    for (int r = 0; r < M1; ++r) {
      int m = tid * M1 + r;
      float bias = b1[m];
#pragma unroll
      for (int g = 0; g < G; ++g) mid[g * 4 * E + m] = gelu(acc[r][g] + bias);
    }
  }
  __syncthreads();
  // ---- FFN2 + residual -> ob; LN2  (W2 column access: lanes over e, coalesced) ----
  {
    const int e = tid % E, gp = tid / E;
    float acc[GPT];
#pragma unroll
    for (int r = 0; r < GPT; ++r) acc[r] = 0.f;
    for (int m = 0; m < 4 * E; m += 8) {
      float wv[8];
#pragma unroll
      for (int ii = 0; ii < 8; ++ii) wv[ii] = W2[(size_t)(m + ii) * E + e];
#pragma unroll
      for (int r = 0; r < GPT; ++r) {
        float xv[8];
        LD8(mid + (gp * GPT + r) * 4 * E + m, xv);
        fma8(acc[r], xv, wv);
      }
    }
#pragma unroll
    for (int r = 0; r < GPT; ++r) {
      int g = gp * GPT + r;
      ob[g * E + e] = b2[e] + hb[g * E + e] + acc[r];
    }
  }
  __syncthreads();
  ln_rows<E>(ob, lng, lnb);
  __syncthreads();
}

// ===================== kernel 1: sub path =====================
__global__ __launch_bounds__(NT, 4) void k_sub(P p) {
  __shared__ __align__(16) u16 X1[8 * G * 64];
  __shared__ __align__(16) u16 X2[3 * G * 64];
  __shared__ __align__(16) float clsb[64];
  __shared__ __align__(16) float uL[4 * 64];
  __shared__ __align__(16) float sbL[4];
  __shared__ __align__(16) float attq[G * 4 * 9];   // also usb qb scratch (needs >=64)
  __shared__ __align__(16) float xbar[G * 4 * 64];
  __shared__ __align__(16) float ob[G * 64];
  __shared__ __align__(16) float hb[G * 64];
  __shared__ __align__(16) float mid[G * 256];
  __shared__ __align__(16) float vec1[G * 64];
  const int tid = threadIdx.x, b0 = blockIdx.x * G;

  // subfield align: X[f][g][e], feats read direct from global (wave-uniform)
  const float* subf = p.in[I_SUB];
  const float* saW = p.in[I_SAW];
  const float* sab = p.in[I_SAB];
  for (int i = tid; i < 11 * 64; i += NT) {
    int f = i / 64, e = i % 64;
    float bias = sab[f * 64 + e];
    float acc[G];
#pragma unroll
    for (int g = 0; g < G; ++g) acc[g] = bias;
    for (int d = 0; d < 32; d += 8) {
      float wv[8];
#pragma unroll
      for (int ii = 0; ii < 8; ++ii) wv[ii] = saW[(size_t)(f * 32 + d + ii) * 64 + e];
#pragma unroll
      for (int g = 0; g < G; ++g) {
        float xv[8];
        LD8(subf + (size_t)(b0 + g) * 352 + f * 32 + d, xv);
        fma8(acc[g], xv, wv);
      }
    }
#pragma unroll
    for (int g = 0; g < G; ++g) {
      if (f < 8) X1[(f * G + g) * 64 + e] = F2B(acc[g]);
      else       X2[((f - 8) * G + g) * 64 + e] = F2B(acc[g]);
    }
  }
  if (tid < 64) clsb[tid] = p.in[I_SCLS][tid];
  __syncthreads();

  // agg1: tcp.flags (subfields 0..7)
  compute_usb<64>(p.in[I_SWQKV], p.in[I_SBQKV], clsb, attq, uL, sbL);
  agg_run<64, 8>(X1, clsb, uL, sbL,
                 p.in[I_SWQKV] + 2 * 64 * 64, p.in[I_SBQKV] + 128,
                 p.in[I_SWO], p.in[I_SBO], p.in[I_SLNG], p.in[I_SLNB],
                 p.in[I_SW1], p.in[I_SB1], p.in[I_SW2], p.in[I_SB2],
                 attq, xbar, ob, hb, mid);
  for (int i = tid; i < G * 64; i += NT) vec1[i] = ob[i];
  if (tid < 64) clsb[tid] = p.in[I_SCLS][64 + tid];
  __syncthreads();

  // agg2: ip.flags (subfields 8..10)
  compute_usb<64>(p.in[I_SWQKV] + 192 * 64, p.in[I_SBQKV] + 192, clsb, attq, uL, sbL);
  agg_run<64, 3>(X2, clsb, uL, sbL,
                 p.in[I_SWQKV] + 192 * 64 + 2 * 64 * 64, p.in[I_SBQKV] + 192 + 128,
                 p.in[I_SWO] + 64 * 64, p.in[I_SBO] + 64,
                 p.in[I_SLNG] + 64, p.in[I_SLNB] + 64,
                 p.in[I_SW1] + 64 * 256, p.in[I_SB1] + 256,
                 p.in[I_SW2] + 256 * 64, p.in[I_SB2] + 64,
                 attq, xbar, ob, hb, mid);

  // parent_al: [:,0] = tcpf @ paW0 + pab0 ; [:,1] = ipf @ paW1 + pab1
  {
    const int pi = tid >> 7, e = tid & 127;
    const float* paW = p.in[I_PAW];
    float bias = p.in[I_PAB][pi * 128 + e];
    float acc[G];
#pragma unroll
    for (int g = 0; g < G; ++g) acc[g] = bias;
    const float* src = pi ? ob : vec1;
    for (int j = 0; j < 64; j += 8) {
      float wv[8];
#pragma unroll
      for (int ii = 0; ii < 8; ++ii) wv[ii] = paW[(size_t)(pi * 64 + j + ii) * 128 + e];
#pragma unroll
      for (int g = 0; g < G; ++g) {
        float xv[8];
        LD8(src + g * 64 + j, xv);
        fma8(acc[g], xv, wv);
      }
    }
#pragma unroll
    for (int g = 0; g < G; ++g)
      p.parent_al[(size_t)(b0 + g) * 256 + pi * 128 + e] = acc[g];
  }
}

// ===================== kernel 2: parent aggs =====================
template <int T, int F, int F0, int PAR, int AI>
__device__ void parent_body(const P& p, int b0, u16* X, float* clsb,
                            float* uL, float* sbL, float* attq, float* xbar,
                            float* ob, float* hb, float* mid) {
  const int tid = threadIdx.x;
  const float* leaf = p.in[I_LEAF];
  const float* laW = p.in[I_LAW];
  const float* lab = p.in[I_LAB];
  for (int i = tid; i < F * 128; i += NT) {
    int f = i / 128, e = i % 128;
    float bias = lab[(F0 + f) * 128 + e];
    float acc[G];
#pragma unroll
    for (int g = 0; g < G; ++g) acc[g] = bias;
    for (int d = 0; d < 32; d += 8) {
      float wv[8];
#pragma unroll
      for (int ii = 0; ii < 8; ++ii)
        wv[ii] = laW[(size_t)((F0 + f) * 32 + d + ii) * 128 + e];
#pragma unroll
      for (int g = 0; g < G; ++g) {
        float xv[8];
        LD8(leaf + (size_t)(b0 + g) * 1088 + (F0 + f) * 32 + d, xv);
        fma8(acc[g], xv, wv);
      }
    }
#pragma unroll
    for (int g = 0; g < G; ++g) X[(f * G + g) * 128 + e] = F2B(acc[g]);
  }
  if (PAR >= 0) {
    for (int i = tid; i < G * 128; i += NT) {
      int g = i / 128, e = i % 128;
      X[((T - 1) * G + g) * 128 + e] =
          F2B(p.parent_al[(size_t)(b0 + g) * 256 + PAR * 128 + e]);
    }
  }
  if (tid < 128) clsb[tid] = p.in[I_PCLS][AI * 128 + tid];
  __syncthreads();
  compute_usb<128>(p.in[I_PWQKV] + (size_t)AI * 384 * 128, p.in[I_PBQKV] + AI * 384,
                   clsb, attq, uL, sbL);
  agg_run<128, T>(X, clsb, uL, sbL,
                  p.in[I_PWQKV] + (size_t)AI * 384 * 128 + 2 * 128 * 128,
                  p.in[I_PBQKV] + AI * 384 + 256,
                  p.in[I_PWO] + (size_t)AI * 128 * 128, p.in[I_PBO] + AI * 128,
                  p.in[I_PLNG] + AI * 128, p.in[I_PLNB] + AI * 128,
                  p.in[I_PW1] + (size_t)AI * 128 * 512, p.in[I_PB1] + AI * 512,
                  p.in[I_PW2] + (size_t)AI * 512 * 128, p.in[I_PB2] + AI * 128,
                  attq, xbar, ob, hb, mid);
  for (int i = tid; i < G * 128; i += NT) {
    int e = i % 128, g = i / 128;
    p.vecs[(size_t)(b0 + g) * 384 + AI * 128 + e] = ob[g * 128 + e];
  }
}

__global__ __launch_bounds__(NT, 4) void k_parent(P p) {
  __shared__ __align__(16) u16 X[16 * G * 128];
  __shared__ __align__(16) float clsb[128];
  __shared__ __align__(16) float uL[4 * 128];
  __shared__ __align__(16) float sbL[4];
  __shared__ __align__(16) float attq[G * 4 * 17];  // also usb qb scratch (>=128)
  __shared__ __align__(16) float xbar[G * 4 * 128];
  __shared__ __align__(16) float ob[G * 128];
  __shared__ __align__(16) float hb[G * 128];
  __shared__ __align__(16) float mid[G * 512];
  const int b0 = blockIdx.x * G;
  if (blockIdx.y == 0)
    parent_body<8, 8, 0, -1, 0>(p, b0, X, clsb, uL, sbL, attq, xbar, ob, hb, mid);
  else if (blockIdx.y == 1)
    parent_body<12, 11, 8, 1, 1>(p, b0, X, clsb, uL, sbL, attq, xbar, ob, hb, mid);
  else
    parent_body<16, 15, 19, 0, 2>(p, b0, X, clsb, uL, sbL, attq, xbar, ob, hb, mid);
}

// ===================== kernel 3: pkt agg + classifier =====================
__global__ __launch_bounds__(NT, 4) void k_pkt(P p) {
  __shared__ __align__(16) u16 X[3 * G * 128];
  __shared__ __align__(16) float clsb[128];
  __shared__ __align__(16) float uL[4 * 128];
  __shared__ __align__(16) float sbL[4];
  __shared__ __align__(16) float attq[128];  // max(G*4*S=64, E=128)
  __shared__ __align__(16) float xbar[G * 4 * 128];
  __shared__ __align__(16) float ob[G * 128];
  __shared__ __align__(16) float hb[G * 128];
  __shared__ __align__(16) float mid[G * 512];
  const int tid = threadIdx.x, b0 = blockIdx.x * G;

  for (int i = tid; i < 3 * G * 128; i += NT) {
    int e = i % 128, g = (i / 128) % G, t = i / (G * 128);
    X[(t * G + g) * 128 + e] = F2B(p.vecs[(size_t)(b0 + g) * 384 + t * 128 + e]);
  }
  if (tid < 128) clsb[tid] = p.in[I_PCLS][3 * 128 + tid];
  __syncthreads();
  compute_usb<128>(p.in[I_PWQKV] + (size_t)3 * 384 * 128, p.in[I_PBQKV] + 3 * 384,
                   clsb, attq, uL, sbL);
  agg_run<128, 3>(X, clsb, uL, sbL,
                  p.in[I_PWQKV] + (size_t)3 * 384 * 128 + 2 * 128 * 128,
                  p.in[I_PBQKV] + 3 * 384 + 256,
                  p.in[I_PWO] + (size_t)3 * 128 * 128, p.in[I_PBO] + 3 * 128,
                  p.in[I_PLNG] + 3 * 128, p.in[I_PLNB] + 3 * 128,
                  p.in[I_PW1] + (size_t)3 * 128 * 512, p.in[I_PB1] + 3 * 512,
                  p.in[I_PW2] + (size_t)3 * 512 * 128, p.in[I_PB2] + 3 * 128,
                  attq, xbar, ob, hb, mid);

  if (tid < G * 2) {
    int g = tid >> 1, c = tid & 1;
    const float* cw = p.in[I_CLFW];
    float acc = p.in[I_CLFB][c];
    for (int j = 0; j < 128; ++j) acc += ob[g * 128 + j] * cw[j * 2 + c];
    p.out[(size_t)(b0 + g) * 2 + c] = acc;
  }
}

extern "C" void kernel_launch(void* const* d_in, const int* in_sizes, int n_in,
                              void* d_out, int out_size, void* d_ws, size_t ws_size,
                              hipStream_t stream) {
  P p;
  for (int i = 0; i < 32; ++i) p.in[i] = (const float*)d_in[i];
  const int B = in_sizes[0] / (34 * 32);
  float* ws = (float*)d_ws;
  p.parent_al = ws;                        // B*256 floats
  p.vecs = ws + (size_t)B * 256;           // B*384 floats
  p.out = (float*)d_out;

  k_sub<<<dim3(B / G), dim3(NT), 0, stream>>>(p);
  k_parent<<<dim3(B / G, 3), dim3(NT), 0, stream>>>(p);
  k_pkt<<<dim3(B / G), dim3(NT), 0, stream>>>(p);
}